// Round 4
// baseline (147.808 us; speedup 1.0000x reference)
//
#include <hip/hip_runtime.h>

#define ND 512   // directions
#define NP 64    // points per ray
#define NR 32    // rank
#define NF 256   // virtual subcarriers
#define RSTRIDE 56  // ushorts per LDS row (112 B: 16B-aligned, 2-way banks only)

typedef __attribute__((ext_vector_type(8))) short bf16x8;   // 8 bf16 = 4 VGPRs
typedef __attribute__((ext_vector_type(4))) float f32x4;

// float -> bf16 (RNE); inputs are finite.
__device__ inline unsigned short f2bf(float x) {
    unsigned u = __builtin_bit_cast(unsigned, x);
    u += 0x7FFFu + ((u >> 16) & 1u);
    return (unsigned short)(u >> 16);
}

// One block per direction d; 256 threads = 4 waves; wave wv owns n-tiles
// 4wv..4wv+3 (64 freqs). Complex projections are decomposed into 4 real
// GEMM products each (signs applied post-MFMA in registers), so A-operands
// stay in natural [p][r] layout: one aligned ds_read_b128 per fragment.
//   conj proj  (att,rad): re = Prr + Pii, im = Pri - Pir
//   plain proj (cumsum) : re = Crr - Cii, im = Cri + Cir
__global__ __launch_bounds__(256, 3) void lrrt_mfma2_kernel(
    const float* __restrict__ att_re, const float* __restrict__ att_im,
    const float* __restrict__ rad_re, const float* __restrict__ rad_im,
    const float* __restrict__ freq_re, const float* __restrict__ freq_im,
    const int* __restrict__ mrl, float* __restrict__ out)
{
    // 0=att_re 1=att_im 2=rad_re 3=rad_im 4=cum_re 5=cum_im : 6*7168B = 42 KB
    __shared__ unsigned short s_mat[6][NP * RSTRIDE];
    __shared__ float s_segtot[256];  // per-(seg,reim,r) segment totals

    const int t = threadIdx.x;
    const int d = blockIdx.x;
    const size_t base = (size_t)d * (NP * NR);
    const int lane = t & 63;
    const int wv = t >> 6;
    const int kg = lane >> 4;       // k-group: rank cols 8kg..8kg+7
    const int m_lo = lane & 15;

    const float* srcs[4] = {att_re, att_im, rad_re, rad_im};

    // --- 1a. stage att/rad as bf16 into padded LDS (coalesced float4) ---
    for (int v = t; v < 4 * 512; v += 256) {
        const int mat = v >> 9;          // 0..3
        const int w = v & 511;           // float4 index within matrix
        const int p = w >> 3;
        const int c = (w & 7) * 4;
        const float4 x = *(const float4*)(srcs[mat] + base + p * NR + c);
        unsigned short* dst = &s_mat[mat][p * RSTRIDE + c];
        dst[0] = f2bf(x.x); dst[1] = f2bf(x.y); dst[2] = f2bf(x.z); dst[3] = f2bf(x.w);
    }

    // --- 1b. segmented cumsum of att along p (4 segs of 16 points) ---
    // t = seg*64 + reim*32 + r
    const int cs_r = t & 31;
    const int cs_reim = (t >> 5) & 1;
    const int cs_seg = t >> 6;
    float vals[16];
    {
        const float* src = cs_reim ? att_im : att_re;
        float run = 0.f;
#pragma unroll
        for (int i = 0; i < 16; ++i) {
            const int p = cs_seg * 16 + i;
            run += src[base + p * NR + cs_r];
            vals[i] = run;
        }
        s_segtot[t] = run;
    }

    // --- 2. B fragments straight into registers (independent of LDS) ---
    // frag(q,ks): lane holds B[k' = 8kg + j][n = 16(4wv+q) + m_lo], ks: re/im
    bf16x8 bfrag[4][2];
#pragma unroll
    for (int q = 0; q < 4; ++q) {
        const int n = 16 * (4 * wv + q) + m_lo;
        const float4* fre = (const float4*)(freq_re + (size_t)n * NR + 8 * kg);
        const float4* fim = (const float4*)(freq_im + (size_t)n * NR + 8 * kg);
        float4 r0 = fre[0], r1 = fre[1];
        float4 i0 = fim[0], i1 = fim[1];
        bf16x8 b0, b1;
        b0[0] = f2bf(r0.x); b0[1] = f2bf(r0.y); b0[2] = f2bf(r0.z); b0[3] = f2bf(r0.w);
        b0[4] = f2bf(r1.x); b0[5] = f2bf(r1.y); b0[6] = f2bf(r1.z); b0[7] = f2bf(r1.w);
        b1[0] = f2bf(i0.x); b1[1] = f2bf(i0.y); b1[2] = f2bf(i0.z); b1[3] = f2bf(i0.w);
        b1[4] = f2bf(i1.x); b1[5] = f2bf(i1.y); b1[6] = f2bf(i1.z); b1[7] = f2bf(i1.w);
        bfrag[q][0] = b0;
        bfrag[q][1] = b1;
    }

    __syncthreads();  // seg totals + staged att/rad visible

    // --- 1c. add segment offsets, store cumsum bf16 to LDS ---
    {
        float off = 0.f;
#pragma unroll
        for (int s = 0; s < 3; ++s)
            if (s < cs_seg) off += s_segtot[s * 64 + cs_reim * 32 + cs_r];
        unsigned short* dst = s_mat[4 + cs_reim];
#pragma unroll
        for (int i = 0; i < 16; ++i) {
            const int p = cs_seg * 16 + i;
            dst[p * RSTRIDE + cs_r] = f2bf(vals[i] + off);
        }
    }
    __syncthreads();  // cumsum visible

    // --- 3. MFMA main loop: 4 m-tiles x 4 n-tiles x 12 real products ---
    const float delta_t = (float)(*mrl) / (float)NP;
    float pre[4] = {0.f, 0.f, 0.f, 0.f};
    float pim[4] = {0.f, 0.f, 0.f, 0.f};
    const f32x4 zero = {0.f, 0.f, 0.f, 0.f};

    for (int mt = 0; mt < 4; ++mt) {
        const int off = (mt * 16 + m_lo) * RSTRIDE + 8 * kg;
        const bf16x8 a_r = *(const bf16x8*)(&s_mat[0][off]);
        const bf16x8 a_i = *(const bf16x8*)(&s_mat[1][off]);
        const bf16x8 r_r = *(const bf16x8*)(&s_mat[2][off]);
        const bf16x8 r_i = *(const bf16x8*)(&s_mat[3][off]);
        const bf16x8 c_r = *(const bf16x8*)(&s_mat[4][off]);
        const bf16x8 c_i = *(const bf16x8*)(&s_mat[5][off]);
#pragma unroll
        for (int q = 0; q < 4; ++q) {
            const bf16x8 vr = bfrag[q][0], vi = bfrag[q][1];
            f32x4 Arr = __builtin_amdgcn_mfma_f32_16x16x32_bf16(a_r, vr, zero, 0, 0, 0);
            f32x4 Aii = __builtin_amdgcn_mfma_f32_16x16x32_bf16(a_i, vi, zero, 0, 0, 0);
            f32x4 Ari = __builtin_amdgcn_mfma_f32_16x16x32_bf16(a_r, vi, zero, 0, 0, 0);
            f32x4 Air = __builtin_amdgcn_mfma_f32_16x16x32_bf16(a_i, vr, zero, 0, 0, 0);
            f32x4 Brr = __builtin_amdgcn_mfma_f32_16x16x32_bf16(r_r, vr, zero, 0, 0, 0);
            f32x4 Bii = __builtin_amdgcn_mfma_f32_16x16x32_bf16(r_i, vi, zero, 0, 0, 0);
            f32x4 Bri = __builtin_amdgcn_mfma_f32_16x16x32_bf16(r_r, vi, zero, 0, 0, 0);
            f32x4 Bir = __builtin_amdgcn_mfma_f32_16x16x32_bf16(r_i, vr, zero, 0, 0, 0);
            f32x4 Crr = __builtin_amdgcn_mfma_f32_16x16x32_bf16(c_r, vr, zero, 0, 0, 0);
            f32x4 Cii = __builtin_amdgcn_mfma_f32_16x16x32_bf16(c_i, vi, zero, 0, 0, 0);
            f32x4 Cri = __builtin_amdgcn_mfma_f32_16x16x32_bf16(c_r, vi, zero, 0, 0, 0);
            f32x4 Cir = __builtin_amdgcn_mfma_f32_16x16x32_bf16(c_i, vr, zero, 0, 0, 0);
#pragma unroll
            for (int i = 0; i < 4; ++i) {
                const int p = mt * 16 + kg * 4 + i;
                const float are = Arr[i] + Aii[i], aim = Ari[i] - Air[i];
                const float bre = Brr[i] + Bii[i], bim = Bri[i] - Bir[i];
                const float ure = Crr[i] - Cii[i], uim = Cri[i] + Cir[i];
                const float qre = bre * are - bim * aim;
                const float qim = bre * aim + bim * are;
                const float w = (p >= 1) ? delta_t : 0.f;  // p=0 excluded from 2nd term
                pre[q] += qre + w * (qre * ure - qim * uim);
                pim[q] += qim + w * (qre * uim + qim * ure);
            }
        }
    }

    // --- 4. reduce across row-groups (lanes ^16, ^32) and emit (planar) ---
    const float scale = delta_t / (float)ND;
#pragma unroll
    for (int q = 0; q < 4; ++q) {
        float re = pre[q], im = pim[q];
        re += __shfl_xor(re, 16, 64); im += __shfl_xor(im, 16, 64);
        re += __shfl_xor(re, 32, 64); im += __shfl_xor(im, 32, 64);
        if (lane < 16) {
            const int f = 16 * (4 * wv + q) + lane;
            atomicAdd(&out[f], re * scale);
            atomicAdd(&out[NF + f], im * scale);
        }
    }
}

extern "C" void kernel_launch(void* const* d_in, const int* in_sizes, int n_in,
                              void* d_out, int out_size, void* d_ws, size_t ws_size,
                              hipStream_t stream) {
    const float* att_re = (const float*)d_in[0];
    const float* att_im = (const float*)d_in[1];
    const float* rad_re = (const float*)d_in[2];
    const float* rad_im = (const float*)d_in[3];
    const float* freq_re = (const float*)d_in[4];
    const float* freq_im = (const float*)d_in[5];
    const int* mrl = (const int*)d_in[6];
    float* out = (float*)d_out;

    // d_out is poisoned 0xAA before every launch; we accumulate with atomics.
    hipMemsetAsync(d_out, 0, (size_t)out_size * sizeof(float), stream);

    lrrt_mfma2_kernel<<<ND, 256, 0, stream>>>(
        att_re, att_im, rad_re, rad_im, freq_re, freq_im, mrl, out);
}

// Round 5
// 89.821 us; speedup vs baseline: 1.6456x; 1.6456x over previous
//
#include <hip/hip_runtime.h>

#define ND 512   // directions
#define NP 64    // points per ray
#define NR 32    // rank
#define NF 256   // virtual subcarriers
#define RSTRIDE 56  // ushorts per LDS row (112 B: 16B-aligned, 2-way banks only)

typedef __attribute__((ext_vector_type(8))) short bf16x8;   // 8 bf16 = 4 VGPRs
typedef __attribute__((ext_vector_type(4))) float f32x4;

// float -> bf16 (RNE); inputs are finite.
__device__ inline unsigned short f2bf(float x) {
    unsigned u = __builtin_bit_cast(unsigned, x);
    u += 0x7FFFu + ((u >> 16) & 1u);
    return (unsigned short)(u >> 16);
}
__device__ inline unsigned pack2(float a, float b) {
    return (unsigned)f2bf(a) | ((unsigned)f2bf(b) << 16);
}

// One block per direction d; 256 threads = 4 waves; wave wv owns n-tiles
// 4wv..4wv+3 (64 freqs). M rows = points p (0..63). All three complex
// projections use the SAME conj pattern via chained MFMAs:
//   re = mfma(x_i, vi, mfma(x_r, vr, 0))      = sum x_r*vr + x_i*vi
//   im = mfma(x_i, -vr, mfma(x_r, vi, 0))     = sum x_r*vi - x_i*vr
// cumsum's im plane is stored NEGATED in LDS so its plain (non-conj)
// projection is expressed by the conj pattern. The cumsum row p=0 is
// zeroed so the second-order term's p>=1 restriction is automatic.
__global__ __launch_bounds__(256, 2) void lrrt_mfma3_kernel(
    const float* __restrict__ att_re, const float* __restrict__ att_im,
    const float* __restrict__ rad_re, const float* __restrict__ rad_im,
    const float* __restrict__ freq_re, const float* __restrict__ freq_im,
    const int* __restrict__ mrl, float* __restrict__ out)
{
    // 0=att_re 1=att_im 2=rad_re 3=rad_im 4=cum_re 5=-cum_im : 42 KB
    __shared__ __align__(16) unsigned short s_mat[6][NP * RSTRIDE];
    __shared__ float s_segtot[256];  // per-(seg,reim,r) segment totals

    const int t = threadIdx.x;
    const int d = blockIdx.x;
    const size_t base = (size_t)d * (NP * NR);
    const int lane = t & 63;
    const int wv = t >> 6;
    const int kg = lane >> 4;       // k-group: rank cols 8kg..8kg+7; rows kg*4..+3
    const int m_lo = lane & 15;

    // --- 1a. stage att/rad as bf16 into padded LDS (no pointer arrays) ---
#pragma unroll
    for (int half = 0; half < 2; ++half) {
        const int w = t + half * 256;        // float4 index 0..511
        const int p = w >> 3;
        const int c = (w & 7) * 4;
        const size_t g = base + (size_t)p * NR + c;
        const int lo = p * RSTRIDE + c;
        float4 x;
        x = *(const float4*)(att_re + g);
        *(uint2*)&s_mat[0][lo] = make_uint2(pack2(x.x, x.y), pack2(x.z, x.w));
        x = *(const float4*)(att_im + g);
        *(uint2*)&s_mat[1][lo] = make_uint2(pack2(x.x, x.y), pack2(x.z, x.w));
        x = *(const float4*)(rad_re + g);
        *(uint2*)&s_mat[2][lo] = make_uint2(pack2(x.x, x.y), pack2(x.z, x.w));
        x = *(const float4*)(rad_im + g);
        *(uint2*)&s_mat[3][lo] = make_uint2(pack2(x.x, x.y), pack2(x.z, x.w));
    }

    // --- 1b. segmented cumsum of att along p (4 segs x 16 points) ---
    // t = seg*64 + reim*32 + r
    const int cs_r = t & 31;
    const int cs_reim = (t >> 5) & 1;
    const int cs_seg = t >> 6;
    float vals[16];
    {
        const float* src = cs_reim ? att_im : att_re;
        float run = 0.f;
#pragma unroll
        for (int i = 0; i < 16; ++i) {
            run += src[base + (cs_seg * 16 + i) * NR + cs_r];
            vals[i] = run;
        }
        s_segtot[t] = run;
    }
    __syncthreads();  // staged att/rad + segment totals visible

    // --- 1c. add segment offsets; store cum_re / -cum_im bf16; zero p=0 row ---
    {
        float off = 0.f;
#pragma unroll
        for (int s = 0; s < 3; ++s)
            if (s < cs_seg) off += s_segtot[s * 64 + cs_reim * 32 + cs_r];
        const float sgn = cs_reim ? -1.f : 1.f;
        unsigned short* dst = s_mat[4 + cs_reim];
#pragma unroll
        for (int i = 0; i < 16; ++i) {
            const int p = cs_seg * 16 + i;
            dst[p * RSTRIDE + cs_r] = (p == 0) ? (unsigned short)0
                                               : f2bf(sgn * (vals[i] + off));
        }
    }
    __syncthreads();  // cumsum visible

    // --- 2. B fragments into registers: vr, vi, and -vr per n-tile ---
    bf16x8 bvr[4], bvi[4], bvn[4];
#pragma unroll
    for (int q = 0; q < 4; ++q) {
        const int n = 16 * (4 * wv + q) + m_lo;
        const float4* fre = (const float4*)(freq_re + (size_t)n * NR + 8 * kg);
        const float4* fim = (const float4*)(freq_im + (size_t)n * NR + 8 * kg);
        const float4 r0 = fre[0], r1 = fre[1];
        const float4 i0 = fim[0], i1 = fim[1];
        bf16x8 vr, vi, vn;
        vr[0] = f2bf(r0.x); vr[1] = f2bf(r0.y); vr[2] = f2bf(r0.z); vr[3] = f2bf(r0.w);
        vr[4] = f2bf(r1.x); vr[5] = f2bf(r1.y); vr[6] = f2bf(r1.z); vr[7] = f2bf(r1.w);
        vi[0] = f2bf(i0.x); vi[1] = f2bf(i0.y); vi[2] = f2bf(i0.z); vi[3] = f2bf(i0.w);
        vi[4] = f2bf(i1.x); vi[5] = f2bf(i1.y); vi[6] = f2bf(i1.z); vi[7] = f2bf(i1.w);
        vn[0] = f2bf(-r0.x); vn[1] = f2bf(-r0.y); vn[2] = f2bf(-r0.z); vn[3] = f2bf(-r0.w);
        vn[4] = f2bf(-r1.x); vn[5] = f2bf(-r1.y); vn[6] = f2bf(-r1.z); vn[7] = f2bf(-r1.w);
        bvr[q] = vr; bvi[q] = vi; bvn[q] = vn;
    }

    // --- 3. MFMA main loop: 4 m-tiles x 4 n-tiles x 6 chained pairs ---
    const float delta_t = (float)(*mrl) / (float)NP;
    float pre[4] = {0.f, 0.f, 0.f, 0.f};
    float pim[4] = {0.f, 0.f, 0.f, 0.f};
    const f32x4 zero = {0.f, 0.f, 0.f, 0.f};

#pragma unroll 1
    for (int mt = 0; mt < 4; ++mt) {
        const int off = (mt * 16 + m_lo) * RSTRIDE + 8 * kg;
        const bf16x8 a_r = *(const bf16x8*)&s_mat[0][off];
        const bf16x8 a_i = *(const bf16x8*)&s_mat[1][off];
        const bf16x8 r_r = *(const bf16x8*)&s_mat[2][off];
        const bf16x8 r_i = *(const bf16x8*)&s_mat[3][off];
        const bf16x8 c_r = *(const bf16x8*)&s_mat[4][off];
        const bf16x8 c_i = *(const bf16x8*)&s_mat[5][off];
#pragma unroll
        for (int q = 0; q < 4; ++q) {
            f32x4 Are = __builtin_amdgcn_mfma_f32_16x16x32_bf16(a_r, bvr[q], zero, 0, 0, 0);
            f32x4 Aim = __builtin_amdgcn_mfma_f32_16x16x32_bf16(a_r, bvi[q], zero, 0, 0, 0);
            f32x4 Bre = __builtin_amdgcn_mfma_f32_16x16x32_bf16(r_r, bvr[q], zero, 0, 0, 0);
            f32x4 Bim = __builtin_amdgcn_mfma_f32_16x16x32_bf16(r_r, bvi[q], zero, 0, 0, 0);
            f32x4 Ure = __builtin_amdgcn_mfma_f32_16x16x32_bf16(c_r, bvr[q], zero, 0, 0, 0);
            f32x4 Uim = __builtin_amdgcn_mfma_f32_16x16x32_bf16(c_r, bvi[q], zero, 0, 0, 0);
            Are = __builtin_amdgcn_mfma_f32_16x16x32_bf16(a_i, bvi[q], Are, 0, 0, 0);
            Aim = __builtin_amdgcn_mfma_f32_16x16x32_bf16(a_i, bvn[q], Aim, 0, 0, 0);
            Bre = __builtin_amdgcn_mfma_f32_16x16x32_bf16(r_i, bvi[q], Bre, 0, 0, 0);
            Bim = __builtin_amdgcn_mfma_f32_16x16x32_bf16(r_i, bvn[q], Bim, 0, 0, 0);
            Ure = __builtin_amdgcn_mfma_f32_16x16x32_bf16(c_i, bvi[q], Ure, 0, 0, 0);
            Uim = __builtin_amdgcn_mfma_f32_16x16x32_bf16(c_i, bvn[q], Uim, 0, 0, 0);
#pragma unroll
            for (int i = 0; i < 4; ++i) {
                const float qre = Bre[i] * Are[i] - Bim[i] * Aim[i];
                const float qim = Bre[i] * Aim[i] + Bim[i] * Are[i];
                const float cre = fmaf(delta_t, Ure[i], 1.0f);  // 1 + dt*u_re
                const float cim = delta_t * Uim[i];             // dt*u_im
                pre[q] = fmaf(qre, cre, fmaf(-qim, cim, pre[q]));
                pim[q] = fmaf(qim, cre, fmaf(qre, cim, pim[q]));
            }
        }
    }

    // --- 4. reduce across row-groups (lanes ^16, ^32) and emit (planar) ---
    const float scale = delta_t / (float)ND;
#pragma unroll
    for (int q = 0; q < 4; ++q) {
        float re = pre[q], im = pim[q];
        re += __shfl_xor(re, 16, 64); im += __shfl_xor(im, 16, 64);
        re += __shfl_xor(re, 32, 64); im += __shfl_xor(im, 32, 64);
        if (lane < 16) {
            const int f = 16 * (4 * wv + q) + lane;
            atomicAdd(&out[f], re * scale);
            atomicAdd(&out[NF + f], im * scale);
        }
    }
}

extern "C" void kernel_launch(void* const* d_in, const int* in_sizes, int n_in,
                              void* d_out, int out_size, void* d_ws, size_t ws_size,
                              hipStream_t stream) {
    const float* att_re = (const float*)d_in[0];
    const float* att_im = (const float*)d_in[1];
    const float* rad_re = (const float*)d_in[2];
    const float* rad_im = (const float*)d_in[3];
    const float* freq_re = (const float*)d_in[4];
    const float* freq_im = (const float*)d_in[5];
    const int* mrl = (const int*)d_in[6];
    float* out = (float*)d_out;

    // d_out is poisoned 0xAA before every launch; we accumulate with atomics.
    hipMemsetAsync(d_out, 0, (size_t)out_size * sizeof(float), stream);

    lrrt_mfma3_kernel<<<ND, 256, 0, stream>>>(
        att_re, att_im, rad_re, rad_im, freq_re, freq_im, mrl, out);
}